// Round 1
// 304.309 us; speedup vs baseline: 1.0603x; 1.0603x over previous
//
#include <hip/hip_runtime.h>

// Round 8: (a) per-sample setup (axis-angle -> rotation -> center, half-extent)
// hoisted out of the sampling kernel into scatter_kernel, stored per SORTED
// position so the hot kernel does one uniform s_load_dwordx8 instead of ~70
// per-wave VALU ops + scattered s_loads; (b) bounds masks folded into the six
// separable axis weights + pure-FMA trilinear tree (removes 8x and/cndmask/add);
// (c) xyz_psf streamed with nontemporal loads so the 128 MB fp16 quad table
// stays L3-resident for the gathers.

#define VOL_N 256
#define S_PSF 64
#define NBUCKET 4096   // 16x16x16 cells of 16^3 voxels
#define TBL_ELEMS (1 << 24)                  // 256^3 entries
#define TBL_BYTES ((size_t)TBL_ELEMS * 8)    // 128 MB

typedef float vf4 __attribute__((ext_vector_type(4)));
typedef _Float16 vh4 __attribute__((ext_vector_type(4)));
typedef _Float16 vh8 __attribute__((ext_vector_type(8)));

// ---- d_ws layout ----
// [0, TBL_BYTES)      fp16 quad table (if ws large enough)
// then ints: hist[4096] | offsets[4096] | perm[N]
// then floats (32B aligned): pre[N][8] = {icx,icy,icz,hx,hy,hz,0,0} in sorted order

__device__ __forceinline__ int bucket_of(const float* __restrict__ sg, int n) {
    int cx = min(max((int)sg[n * 3 + 0], 0), VOL_N - 1) >> 4;
    int cy = min(max((int)sg[n * 3 + 1], 0), VOL_N - 1) >> 4;
    int cz = min(max((int)sg[n * 3 + 2], 0), VOL_N - 1) >> 4;
    int m = 0;
    #pragma unroll
    for (int b = 0; b < 4; b++) {
        m |= (((cx >> b) & 1) << (3 * b))
           | (((cy >> b) & 1) << (3 * b + 1))
           | (((cz >> b) & 1) << (3 * b + 2));
    }
    return m;
}

__global__ void zero_hist_kernel(int* __restrict__ ws) {
    int i = blockIdx.x * blockDim.x + threadIdx.x;
    if (i < NBUCKET) ws[i] = 0;
}

__global__ void hist_kernel(const float* __restrict__ sg, int* __restrict__ ws, int N) {
    int n = blockIdx.x * blockDim.x + threadIdx.x;
    if (n >= N) return;
    atomicAdd(&ws[bucket_of(sg, n)], 1);
}

__global__ __launch_bounds__(1024) void scan_kernel(int* __restrict__ ws) {
    __shared__ int tmp[1024];
    const int t = threadIdx.x;
    int h0 = ws[t * 4 + 0], h1 = ws[t * 4 + 1], h2 = ws[t * 4 + 2], h3 = ws[t * 4 + 3];
    int s = h0 + h1 + h2 + h3;
    tmp[t] = s;
    __syncthreads();
    for (int off = 1; off < 1024; off <<= 1) {
        int v = (t >= off) ? tmp[t - off] : 0;
        __syncthreads();
        tmp[t] += v;
        __syncthreads();
    }
    int excl = tmp[t] - s;
    ws[NBUCKET + t * 4 + 0] = excl;
    ws[NBUCKET + t * 4 + 1] = excl + h0;
    ws[NBUCKET + t * 4 + 2] = excl + h0 + h1;
    ws[NBUCKET + t * 4 + 3] = excl + h0 + h1 + h2;
}

// Scatter + fused per-sample setup. Each thread owns one sample: computes the
// rotated center (pre-scaled into voxel-index space) and half extents, writes
// them at the SORTED position so the sampling kernel reads them contiguously.
__global__ void scatter_kernel(const float* __restrict__ sg,
                               const float* __restrict__ ax,
                               const float* __restrict__ bound,
                               int* __restrict__ ws,
                               float* __restrict__ pre, int N) {
    int n = blockIdx.x * blockDim.x + threadIdx.x;
    if (n >= N) return;
    int b = bucket_of(sg, n);
    int pos = atomicAdd(&ws[NBUCKET + b], 1);
    ws[2 * NBUCKET + pos] = n;

    const float vx = ax[n * 6 + 0], vy = ax[n * 6 + 1], vz = ax[n * 6 + 2];
    const float tx = ax[n * 6 + 3], ty = ax[n * 6 + 4], tz = ax[n * 6 + 5];

    const float theta = sqrtf(vx * vx + vy * vy + vz * vz);
    const float kinv = 1.0f / fmaxf(theta, 1e-12f);
    const float kx = vx * kinv, ky = vy * kinv, kz = vz * kinv;
    const float ct = __cosf(theta), st = __sinf(theta);
    const float oc = 1.0f - ct;

    const float r00 = 1.0f + oc * (-(ky * ky + kz * kz));
    const float r01 = -st * kz + oc * kx * ky;
    const float r02 =  st * ky + oc * kx * kz;
    const float r10 =  st * kz + oc * kx * ky;
    const float r11 = 1.0f + oc * (-(kx * kx + kz * kz));
    const float r12 = -st * kx + oc * ky * kz;
    const float r20 = -st * ky + oc * kx * kz;
    const float r21 =  st * kx + oc * ky * kz;
    const float r22 = 1.0f + oc * (-(kx * kx + ky * ky));

    const float px = sg[n * 3 + 0] + tx;
    const float py = sg[n * 3 + 1] + ty;
    const float pz = sg[n * 3 + 2] + tz;

    const float cx = r00 * px + r01 * py + r02 * pz;
    const float cy = r10 * px + r11 * py + r12 * pz;
    const float cz = r20 * px + r21 * py + r22 * pz;

    const float hx = (bound[n * 6 + 3] - bound[n * 6 + 0]) * 0.5f;
    const float hy = (bound[n * 6 + 4] - bound[n * 6 + 1]) * 0.5f;
    const float hz = (bound[n * 6 + 5] - bound[n * 6 + 2]) * 0.5f;

    const float scale = (float)VOL_N / (float)(VOL_N - 1);
    // ix = (cx + ox)*scale - 0.5 == fma(ox, scale, icx) with icx = cx*scale-0.5
    float4 A = make_float4(cx * scale - 0.5f, cy * scale - 0.5f,
                           cz * scale - 0.5f, hx);
    float4 B = make_float4(hy, hz, 0.0f, 0.0f);
    *(float4*)(pre + (size_t)pos * 8)     = A;
    *(float4*)(pre + (size_t)pos * 8 + 4) = B;
}

// Build fp16 quad table tbl[z][y][x] = {v[y][x], v[y][x+1], v[y+1][x],
// v[y+1][x+1]} with x=255/y=255 neighbors duplicated. Each thread covers TWO
// consecutive x -> one contiguous 16 B store; consecutive threads contiguous.
__global__ __launch_bounds__(256) void build_quad_kernel(
    const float* __restrict__ vol, vh4* __restrict__ tbl) {
    const int t = blockIdx.x * 256 + threadIdx.x;   // [0, 256*256*128)
    const int x2 = (t & 127) << 1;
    const int y = (t >> 7) & 255;
    const int z = t >> 15;
    const float* r0 = vol + (z << 16) + (y << 8);
    const float* r1 = vol + (z << 16) + (min(y + 1, VOL_N - 1) << 8);
    const float2 a = *(const float2*)(r0 + x2);
    const float2 b = *(const float2*)(r1 + x2);
    const float a2 = (x2 == VOL_N - 2) ? a.y : r0[x2 + 2];
    const float b2 = (x2 == VOL_N - 2) ? b.y : r1[x2 + 2];

    union { vh8 h; vf4 f; } o;
    o.h = (vh8){(_Float16)a.x, (_Float16)a.y, (_Float16)b.x, (_Float16)b.y,
                (_Float16)a.y, (_Float16)a2,  (_Float16)b.y, (_Float16)b2};
    *(vf4*)(tbl + ((z << 16) + (y << 8) + x2)) = o.f;
}

template <bool USE_TBL, bool USE_PRE>
__global__ __launch_bounds__(256, 4) void psf_sample_kernel(
    const float* __restrict__ vol,        // [256][256][256] (z,y,x)
    const vh4* __restrict__ tbl,          // fp16 quad table (USE_TBL)
    const float* __restrict__ sampleGrid, // [N][3]
    const float* __restrict__ ax,         // [N][6]
    const float* __restrict__ bound,      // [N][2][3]
    const float* __restrict__ invcov,     // [3][3]
    const float* __restrict__ xyz_psf,    // [N][64][3]
    const int* __restrict__ perm,         // sorted pos -> n (USE_PRE)
    const float* __restrict__ pre,        // [N][8] precomputed setup (USE_PRE)
    float* __restrict__ out,              // [N]
    int N)
{
    const int lane = threadIdx.x & 63;

    // XCD-contiguous swizzle so each XCD sweeps a contiguous sorted range
    int bid = blockIdx.x;
    const int nb = gridDim.x;
    if ((nb & 7) == 0) bid = (bid & 7) * (nb >> 3) + (bid >> 3);

    const int ii = bid * (blockDim.x >> 6) + (threadIdx.x >> 6);
    if (ii >= N) return;
    // wave-uniform indices -> SGPRs so all per-sample loads become s_load
    const int i = __builtin_amdgcn_readfirstlane(ii);
    const int n = USE_PRE ? __builtin_amdgcn_readfirstlane(perm[i]) : i;

    const float scale = (float)VOL_N / (float)(VOL_N - 1);
    float icx, icy, icz, hx, hy, hz;
    if (USE_PRE) {
        const float4 A = *(const float4*)(pre + (size_t)i * 8);
        const float4 B = *(const float4*)(pre + (size_t)i * 8 + 4);
        icx = A.x; icy = A.y; icz = A.z; hx = A.w; hy = B.x; hz = B.y;
    } else {
        const float vx = ax[n * 6 + 0], vy = ax[n * 6 + 1], vz = ax[n * 6 + 2];
        const float tx = ax[n * 6 + 3], ty = ax[n * 6 + 4], tz = ax[n * 6 + 5];
        const float theta = sqrtf(vx * vx + vy * vy + vz * vz);
        const float kinv = 1.0f / fmaxf(theta, 1e-12f);
        const float kx = vx * kinv, ky = vy * kinv, kz = vz * kinv;
        const float ct = __cosf(theta), st = __sinf(theta);
        const float oc = 1.0f - ct;
        const float r00 = 1.0f + oc * (-(ky * ky + kz * kz));
        const float r01 = -st * kz + oc * kx * ky;
        const float r02 =  st * ky + oc * kx * kz;
        const float r10 =  st * kz + oc * kx * ky;
        const float r11 = 1.0f + oc * (-(kx * kx + kz * kz));
        const float r12 = -st * kx + oc * ky * kz;
        const float r20 = -st * ky + oc * kx * kz;
        const float r21 =  st * kx + oc * ky * kz;
        const float r22 = 1.0f + oc * (-(kx * kx + ky * ky));
        const float px = sampleGrid[n * 3 + 0] + tx;
        const float py = sampleGrid[n * 3 + 1] + ty;
        const float pz = sampleGrid[n * 3 + 2] + tz;
        icx = (r00 * px + r01 * py + r02 * pz) * scale - 0.5f;
        icy = (r10 * px + r11 * py + r12 * pz) * scale - 0.5f;
        icz = (r20 * px + r21 * py + r22 * pz) * scale - 0.5f;
        hx = (bound[n * 6 + 3] - bound[n * 6 + 0]) * 0.5f;
        hy = (bound[n * 6 + 4] - bound[n * 6 + 1]) * 0.5f;
        hz = (bound[n * 6 + 5] - bound[n * 6 + 2]) * 0.5f;
    }

    const float m00 = invcov[0], m01 = invcov[1], m02 = invcov[2];
    const float m10 = invcov[3], m11 = invcov[4], m12 = invcov[5];
    const float m20 = invcov[6], m21 = invcov[7], m22 = invcov[8];

    // ---- per-lane PSF point (streaming, zero reuse -> nontemporal) ----
    const int pbase = (n * S_PSF + lane) * 3;     // < 2^24*3, fits int
    const float gx = __builtin_nontemporal_load(xyz_psf + pbase + 0);
    const float gy = __builtin_nontemporal_load(xyz_psf + pbase + 1);
    const float gz = __builtin_nontemporal_load(xyz_psf + pbase + 2);
    const float ox = gx * hx, oy = gy * hy, oz = gz * hz;

    const float ix = fmaf(ox, scale, icx);
    const float iy = fmaf(oy, scale, icy);
    const float iz = fmaf(oz, scale, icz);

    const float x0f = floorf(ix), y0f = floorf(iy), z0f = floorf(iz);
    const float fx = ix - x0f, fy = iy - y0f, fz = iz - z0f;
    const int x0 = (int)x0f, y0 = (int)y0f, z0 = (int)z0f;

    // validity folded into separable axis weights (corner mask == product)
    const float wx0 = ((unsigned)x0       < (unsigned)VOL_N) ? (1.0f - fx) : 0.0f;
    const float wx1 = ((unsigned)(x0 + 1) < (unsigned)VOL_N) ? fx          : 0.0f;
    const float wy0 = ((unsigned)y0       < (unsigned)VOL_N) ? (1.0f - fy) : 0.0f;
    const float wy1 = ((unsigned)(y0 + 1) < (unsigned)VOL_N) ? fy          : 0.0f;
    const float wz0 = ((unsigned)z0       < (unsigned)VOL_N) ? (1.0f - fz) : 0.0f;
    const float wz1 = ((unsigned)(z0 + 1) < (unsigned)VOL_N) ? fz          : 0.0f;

    float v000, v001, v010, v011, v100, v101, v110, v111;
    if (USE_TBL) {
        const int xg = min(max(x0, 0), VOL_N - 1);
        const int yg = min(max(y0, 0), VOL_N - 1);
        const int zg0 = min(max(z0, 0), VOL_N - 1);
        const int zg1 = min(max(z0 + 1, 0), VOL_N - 1);
        const int common = (yg << 8) + xg;
        const vh4 p0 = tbl[(zg0 << 16) + common];
        const vh4 p1 = tbl[(zg1 << 16) + common];
        const bool lox = x0 < 0;   // x0==-1 with x1==0 valid
        const bool loy = y0 < 0;
        // slots: {y0x0, y0x1, y1x0, y1x1}; hi-edges are duplicate-baked.
        float s00 = p0.x, s01 = p0.y, s10 = p0.z, s11 = p0.w;
        float a01 = lox ? s00 : s01, a11 = lox ? s10 : s11;
        v000 = s00;                 v001 = a01;
        v010 = loy ? s00 : s10;     v011 = loy ? a01 : a11;
        s00 = p1.x; s01 = p1.y; s10 = p1.z; s11 = p1.w;
        a01 = lox ? s00 : s01; a11 = lox ? s10 : s11;
        v100 = s00;                 v101 = a01;
        v110 = loy ? s00 : s10;     v111 = loy ? a01 : a11;
    } else {
        const int xc0 = min(max(x0, 0), VOL_N - 1);
        const int xc1 = min(max(x0 + 1, 0), VOL_N - 1);
        const int yc0 = min(max(y0, 0), VOL_N - 1);
        const int yc1 = min(max(y0 + 1, 0), VOL_N - 1);
        const int zc0 = min(max(z0, 0), VOL_N - 1);
        const int zc1 = min(max(z0 + 1, 0), VOL_N - 1);
        const int zo0 = zc0 << 16, zo1 = zc1 << 16;
        const int yo0 = yc0 << 8, yo1 = yc1 << 8;
        v000 = vol[zo0 + yo0 + xc0];
        v001 = vol[zo0 + yo0 + xc1];
        v010 = vol[zo0 + yo1 + xc0];
        v011 = vol[zo0 + yo1 + xc1];
        v100 = vol[zo1 + yo0 + xc0];
        v101 = vol[zo1 + yo0 + xc1];
        v110 = vol[zo1 + yo1 + xc0];
        v111 = vol[zo1 + yo1 + xc1];
    }

    // pure-FMA separable trilinear (masked weights zero invalid corners)
    const float r0 = fmaf(v001, wx1, v000 * wx0);
    const float r1 = fmaf(v011, wx1, v010 * wx0);
    const float r2 = fmaf(v101, wx1, v100 * wx0);
    const float r3 = fmaf(v111, wx1, v110 * wx0);
    const float s0 = fmaf(r1, wy1, r0 * wy0);
    const float s1 = fmaf(r3, wy1, r2 * wy0);
    const float acc = fmaf(s1, wz1, s0 * wz0);

    const float qx = fmaf(m00, ox, fmaf(m01, oy, m02 * oz));
    const float qy = fmaf(m10, ox, fmaf(m11, oy, m12 * oz));
    const float qz = fmaf(m20, ox, fmaf(m21, oy, m22 * oz));
    const float q = fmaf(ox, qx, fmaf(oy, qy, oz * qz));
    const float w = __expf(-0.5f * q);

    float num = acc * w;
    float den = w;
    #pragma unroll
    for (int m = 32; m >= 1; m >>= 1) {
        num += __shfl_xor(num, m, 64);
        den += __shfl_xor(den, m, 64);
    }
    if (lane == 0) out[n] = num / den;
}

extern "C" void kernel_launch(void* const* d_in, const int* in_sizes, int n_in,
                              void* d_out, int out_size, void* d_ws, size_t ws_size,
                              hipStream_t stream) {
    const float* x        = (const float*)d_in[0];
    const float* sg       = (const float*)d_in[1];
    const float* ax       = (const float*)d_in[2];
    const float* bound    = (const float*)d_in[3];
    const float* invcov   = (const float*)d_in[4];
    const float* xyz_psf  = (const float*)d_in[5];
    float* out            = (float*)d_out;

    const int N = in_sizes[1] / 3;           // sampleGrid is [N][3]
    const size_t sort_bytes = (size_t)(2 * NBUCKET + N) * sizeof(int);
    const size_t sort_pad   = (sort_bytes + 31) & ~(size_t)31;   // align pre to 32B
    const size_t pre_bytes  = (size_t)N * 8 * sizeof(float);

    const bool use_tbl  = ws_size >= TBL_BYTES + sort_pad + pre_bytes;
    const bool use_sort = use_tbl || ws_size >= sort_pad + pre_bytes;

    vh4* tbl = use_tbl ? (vh4*)d_ws : nullptr;
    char* base = (char*)d_ws + (use_tbl ? TBL_BYTES : 0);
    int* sort_ws = (int*)base;
    float* pre = (float*)(base + sort_pad);

    int* perm = nullptr;
    if (use_sort) {
        zero_hist_kernel<<<(NBUCKET + 255) / 256, 256, 0, stream>>>(sort_ws);
        hist_kernel<<<(N + 255) / 256, 256, 0, stream>>>(sg, sort_ws, N);
        scan_kernel<<<1, 1024, 0, stream>>>(sort_ws);
        scatter_kernel<<<(N + 255) / 256, 256, 0, stream>>>(sg, ax, bound, sort_ws, pre, N);
        perm = sort_ws + 2 * NBUCKET;
    }
    if (use_tbl) {
        build_quad_kernel<<<(VOL_N * VOL_N * VOL_N / 2) / 256, 256, 0, stream>>>(x, tbl);
    }

    dim3 block(256);
    dim3 grid((N + 3) / 4);                  // 4 waves (samples) per block
    if (use_tbl) {
        psf_sample_kernel<true, true><<<grid, block, 0, stream>>>(
            x, tbl, sg, ax, bound, invcov, xyz_psf, perm, pre, out, N);
    } else if (use_sort) {
        psf_sample_kernel<false, true><<<grid, block, 0, stream>>>(
            x, nullptr, sg, ax, bound, invcov, xyz_psf, perm, pre, out, N);
    } else {
        psf_sample_kernel<false, false><<<grid, block, 0, stream>>>(
            x, nullptr, sg, ax, bound, invcov, xyz_psf, nullptr, nullptr, out, N);
    }
}